// Round 8
// baseline (357.698 us; speedup 1.0000x reference)
//
#include <hip/hip_runtime.h>
#include <math.h>

// ---------------------------------------------------------------------------
// GCN: 3x (MFMA GEMM(+dis scale, fp8 table out) -> pull-aggregate -> tanh)
//      -> fused pool+head
// R23: two occupancy/overhead cuts guided by the full time budget
//      (fills 132us fixed + agg 107 + gemm 36 + csr 25 + pool 8):
//      - gemm_mfma: 16 rows/wave (was 32) -> 3128 waves = 3.05/SIMD (was
//        1.5/SIMD, occupancy-starved). acc halves to 32 regs.
//      - aggregate3: eidx LDS staging + __syncthreads REMOVED (csr16 window
//        is ~1KB, 16-lane broadcast, L1-resident — staging was pure
//        critical-path overhead; m169 lesson: don't stage cache-fit data).
//      Rest identical to R22/R21 (branchless clamp gathers, distributed
//      epilogue, fast tanh, bucketed CSR build).
// ---------------------------------------------------------------------------

#define BLK_EDGES 4096
#define MAXB 128          // max dst-buckets for CSR build (N<=65536)
#define NPB 8             // nodes per aggregate block (8 waves x 1 node)
#define WS_STRIDE 136     // LDS row stride for W^T (elements; 272B, 16B-aligned)

typedef __attribute__((ext_vector_type(8))) short bf16x8;
typedef __attribute__((ext_vector_type(4))) float f32x4;
typedef __attribute__((ext_vector_type(2))) float f32x2;

static __device__ inline unsigned short f2bf(float f) {
    unsigned u = __float_as_uint(f);
    unsigned r = (u + 0x7FFFu + ((u >> 16) & 1u)) >> 16;   // RNE
    return (unsigned short)r;
}
static __device__ inline float bf_lo(unsigned u) { return __uint_as_float(u << 16); }
static __device__ inline float bf_hi(unsigned u) { return __uint_as_float(u & 0xFFFF0000u); }
static __device__ inline unsigned char f2fp8(float v) {
    v = fminf(fmaxf(v, -240.f), 240.f);                    // avoid e4m3 NaN
    int u = __builtin_amdgcn_cvt_pk_fp8_f32(v, v, 0, false);
    return (unsigned char)(u & 0xFF);
}
// tanh(x) = sign(x) * (1 - 2/(1+e^{2|x|})) — v_exp + v_rcp, ~6 inst.
static __device__ inline float fast_tanh(float x) {
    float ax = fabsf(x);
    float e = __expf(2.0f * ax);
    float r = fmaf(-2.0f, __builtin_amdgcn_rcpf(e + 1.0f), 1.0f);
    return copysignf(r, x);
}

// ---- bucket histogram (blocks < NBLK) + weight transpose (blocks >= NBLK) -
// Also zeroes the hs "zero row" (row N) used by branchless masked gathers.
__global__ __launch_bounds__(256) void blk_hist_prep(const int* __restrict__ dst,
        int* __restrict__ histT, int E, int NBLK, int NB,
        const float* __restrict__ W0, const float* __restrict__ W1,
        const float* __restrict__ W2, unsigned short* __restrict__ wt0,
        unsigned short* __restrict__ wt1, unsigned short* __restrict__ wt2,
        unsigned char* __restrict__ hs, int N) {
    __shared__ int h[MAXB];
    int blk = blockIdx.x, t = threadIdx.x;
    if (blk >= NBLK) {
        if (blk == NBLK && t < 32)            // zero row N of hs (128B)
            ((unsigned*)(hs + (size_t)N * 128))[t] = 0u;
        int i = (blk - NBLK) * 256 + t;       // covers 3*16384 exactly (192 blocks)
        int w = i >> 14, j = i & 16383;
        int k = j >> 7, n2 = j & 127;
        const float* Wp = (w == 0) ? W0 : (w == 1) ? W1 : W2;
        unsigned short* Wt = (w == 0) ? wt0 : (w == 1) ? wt1 : wt2;
        Wt[n2 * 128 + k] = f2bf(Wp[k * 128 + n2]);
        return;
    }
    for (int i = t; i < NB; i += 256) h[i] = 0;
    __syncthreads();
    int lo = blk * BLK_EDGES;
    int hi = min(E, lo + BLK_EDGES);
    for (int i = lo + t; i < hi; i += 256)
        atomicAdd(&h[dst[i] >> 9], 1);
    __syncthreads();
    for (int i = t; i < NB; i += 256) histT[i * NBLK + blk] = h[i];
}

// ---- 2-kernel scan (per-chunk exclusive + chunk offsets; consumers fold) --
__global__ void scan_block(const int* __restrict__ cnt, int* __restrict__ off,
                           int* __restrict__ bsum, int n) {
    __shared__ int lds[256];
    int t = threadIdx.x;
    int i = blockIdx.x * 256 + t;
    int v = (i < n) ? cnt[i] : 0;
    lds[t] = v;
    __syncthreads();
    for (int d = 1; d < 256; d <<= 1) {
        int add = (t >= d) ? lds[t - d] : 0;
        __syncthreads();
        lds[t] += add;
        __syncthreads();
    }
    if (i < n) off[i] = lds[t] - v;      // exclusive within 256-chunk
    if (t == 255) bsum[blockIdx.x] = lds[255];
}

__global__ void scan_top(const int* __restrict__ bsum, int* __restrict__ boff,
                         int nblocks) {
    __shared__ int lds[256];
    int t = threadIdx.x;
    int v = (t < nblocks) ? bsum[t] : 0;
    lds[t] = v;
    __syncthreads();
    for (int d = 1; d < 256; d <<= 1) {
        int add = (t >= d) ? lds[t - d] : 0;
        __syncthreads();
        lds[t] += add;
        __syncthreads();
    }
    if (t < nblocks) boff[t] = lds[t] - v;   // exclusive chunk offsets
}

// ---- scatter packed edges into private (block,bucket) runs ----------------
__global__ __launch_bounds__(256) void scatter_packed(const int* __restrict__ src,
        const int* __restrict__ dst, const int* __restrict__ P,
        const int* __restrict__ boff, unsigned* __restrict__ packed,
        int E, int NBLK, int NB) {
    __shared__ int cur[MAXB];
    int blk = blockIdx.x, t = threadIdx.x;
    for (int i = t; i < NB; i += 256) {
        int idx = i * NBLK + blk;
        cur[i] = P[idx] + boff[idx >> 8];
    }
    __syncthreads();
    int lo = blk * BLK_EDGES;
    int hi = min(E, lo + BLK_EDGES);
    for (int i = lo + t; i < hi; i += 256) {
        int d = dst[i];
        int pos = atomicAdd(&cur[d >> 9], 1);   // LDS atomic, block-local
        packed[pos] = ((unsigned)d << 16) | (unsigned)src[i];
    }
}

// ---- per-bucket: node counts, local scan -> off/dis, fill ushort CSR ------
__global__ __launch_bounds__(256) void bucket_build(const unsigned* __restrict__ packed,
        const int* __restrict__ P, const int* __restrict__ boff, int* __restrict__ off,
        float* __restrict__ dis, unsigned short* __restrict__ csr16,
        int E, int NBLK, int N, int NB) {
    __shared__ int cnt[512];
    __shared__ int loc[512];
    __shared__ int ps[256];
    int b = blockIdx.x, t = threadIdx.x;
    int i0 = b * NBLK, i1 = (b + 1) * NBLK;
    int start = P[i0] + boff[i0 >> 8];
    int end   = (b == NB - 1) ? E : (P[i1] + boff[i1 >> 8]);
    cnt[t] = 0; cnt[t + 256] = 0;
    __syncthreads();
    for (int i = start + t; i < end; i += 256)
        atomicAdd(&cnt[(packed[i] >> 16) & 511], 1);
    __syncthreads();
    int c0 = cnt[2 * t], c1 = cnt[2 * t + 1];
    ps[t] = c0 + c1;
    __syncthreads();
    for (int d = 1; d < 256; d <<= 1) {
        int add = (t >= d) ? ps[t - d] : 0;
        __syncthreads();
        ps[t] += add;
        __syncthreads();
    }
    int pexcl = ps[t] - (c0 + c1);
    loc[2 * t]     = start + pexcl;
    loc[2 * t + 1] = start + pexcl + c0;
    __syncthreads();
    int node0 = b * 512;
    for (int l = t; l < 512; l += 256) {
        int node = node0 + l;
        if (node < N) {
            off[node] = loc[l];
            dis[node] = rsqrtf((float)cnt[l] + 1.0f);
        }
    }
    if (b == NB - 1 && t == 0) off[N] = E;
    __syncthreads();
    for (int i = start + t; i < end; i += 256) {
        unsigned p = packed[i];
        int l = (p >> 16) & 511;
        int pos = atomicAdd(&loc[l], 1);
        csr16[pos] = (unsigned short)(p & 0xFFFFu);
    }
}

// ---- MFMA GEMM: Hs8[r] = fp8( dis[r] * (A[r] @ W) ) -----------------------
// 256 threads (4 waves), 16 rows/wave, 64 rows/block: 3128 waves total
// (3.05/SIMD) vs 1.5/SIMD at 32 rows/wave — latency hiding was the gap.
template<int IN_F32>
__global__ __launch_bounds__(256) void gemm_mfma(const void* __restrict__ Av,
        const unsigned short* __restrict__ Wt, const float* __restrict__ dis,
        unsigned char* __restrict__ Hs8, int n) {
    __shared__ unsigned short Ws[128 * WS_STRIDE];   // 34.8 KB
    int t = threadIdx.x;
    for (int i = t; i < 128 * 16; i += 256) {
        int r = i >> 4, j = i & 15;
        uint4 u = ((const uint4*)(Wt + r * 128))[j];
        *(uint4*)&Ws[r * WS_STRIDE + j * 8] = u;
    }
    __syncthreads();

    int wave = t >> 6, lane = t & 63;
    int quad = lane >> 4, l16 = lane & 15;
    int row0 = blockIdx.x * 64 + wave * 16;

    int ra0 = row0 + l16; if (ra0 >= n) ra0 = n - 1;

    f32x4 acc[8];
    const f32x4 z = {0.f, 0.f, 0.f, 0.f};
#pragma unroll
    for (int ni = 0; ni < 8; ++ni) acc[ni] = z;

#pragma unroll
    for (int ks = 0; ks < 4; ++ks) {
        int kof = ks * 32 + quad * 8;
        bf16x8 a0;
        if (IN_F32) {
            const float* A0 = (const float*)Av + (size_t)ra0 * 128 + kof;
            float4 p0 = ((const float4*)A0)[0], p1 = ((const float4*)A0)[1];
            a0[0] = (short)f2bf(p0.x); a0[1] = (short)f2bf(p0.y);
            a0[2] = (short)f2bf(p0.z); a0[3] = (short)f2bf(p0.w);
            a0[4] = (short)f2bf(p1.x); a0[5] = (short)f2bf(p1.y);
            a0[6] = (short)f2bf(p1.z); a0[7] = (short)f2bf(p1.w);
        } else {
            a0 = *(const bf16x8*)((const unsigned short*)Av + (size_t)ra0 * 128 + kof);
        }
        bf16x8 b[8];
#pragma unroll
        for (int ni = 0; ni < 8; ++ni)
            b[ni] = *(const bf16x8*)&Ws[(ni * 16 + l16) * WS_STRIDE + kof];
#pragma unroll
        for (int ni = 0; ni < 8; ++ni)
            acc[ni] = __builtin_amdgcn_mfma_f32_16x16x32_bf16(a0, b[ni], acc[ni], 0, 0, 0);
    }
    int rb = row0 + quad * 4;
#pragma unroll
    for (int reg = 0; reg < 4; ++reg) {
        int r = rb + reg;
        if (r < n) {
            float dv = dis[r];
#pragma unroll
            for (int ni = 0; ni < 8; ++ni)
                Hs8[(size_t)r * 128 + ni * 16 + l16] = f2fp8(acc[ni][reg] * dv);
        }
    }
}

// ---- pull aggregation over fp8 table: no LDS, no sync, branchless ---------
// 8 nodes per 512-thread block (8 waves x 1 node). csr16 window (~1KB) is
// L1-resident 16-lane-broadcast — read directly, no staging. 16-edge
// batches (4 j-steps x 4 edge streams), uint2 (8 fp8) per lane; OOR slots
// clamp to zeroed row N. Packed cvt, 2-step shfl_xor reduce, distributed
// epilogue (group g owns feats 8fq+2g..+1).
template<int DO_TANH>
__global__ __launch_bounds__(512) void aggregate3(const unsigned char* __restrict__ hs,
    const unsigned short* __restrict__ csr, const int* __restrict__ off,
    const float* __restrict__ dis, const float* __restrict__ bias,
    unsigned* __restrict__ outp, int n) {
    int t = threadIdx.x;
    int node = blockIdx.x * NPB + (t >> 6);
    if (node >= n) return;
    int lane = t & 63;
    int g = lane >> 4;                      // edge stream 0..3
    int fq = lane & 15;                     // feature octet
    unsigned fob = (unsigned)fq << 3;       // feature byte offset in row

    int e0 = off[node];
    int e1 = off[node + 1];
    int m = e1 - e0;

    // self-loop bytes for this lane's pair (feats 8fq+2g, +1): issue early
    unsigned sv = *(const unsigned short*)(hs + (((unsigned)node) << 7) + fob + 2 * g);

    float a0 = 0.f, a1 = 0.f, a2 = 0.f, a3 = 0.f;
    float a4 = 0.f, a5 = 0.f, a6 = 0.f, a7 = 0.f;
    auto cadd = [&](uint2 v) {
        f32x2 p0 = __builtin_amdgcn_cvt_pk_f32_fp8((int)v.x, false);
        f32x2 p1 = __builtin_amdgcn_cvt_pk_f32_fp8((int)v.x, true);
        f32x2 p2 = __builtin_amdgcn_cvt_pk_f32_fp8((int)v.y, false);
        f32x2 p3 = __builtin_amdgcn_cvt_pk_f32_fp8((int)v.y, true);
        a0 += p0.x; a1 += p0.y; a2 += p1.x; a3 += p1.y;
        a4 += p2.x; a5 += p2.y; a6 += p3.x; a7 += p3.y;
    };
    uint2 va[4], vb[4];
    auto sumB = [&](uint2* v) {
#pragma unroll
        for (int j = 0; j < 4; ++j) cadd(v[j]);
    };
    // branchless batch: edge e = i + g + 4j; e >= m -> zero row n
    auto loadB = [&](int i, uint2* v) {
#pragma unroll
        for (int j = 0; j < 4; ++j) {
            int e = i + g + 4 * j;
            int idx = csr[e0 + e];                   // speculative (padded)
            idx = (e < m) ? idx : n;                 // clamp to zero row
            v[j] = *(const uint2*)(hs + ((unsigned)idx << 7) + fob);
        }
    };

    int B = (m + 15) >> 4;          // 16-edge batches, no tail
    if (B) {
        loadB(0, va);
        int k = 1;
        for (; k + 1 < B; k += 2) {
            loadB(k << 4, vb);       sumB(va);
            loadB((k + 1) << 4, va); sumB(vb);
        }
        if (k < B) { loadB(k << 4, vb); sumB(va); sumB(vb); }
        else       { sumB(va); }
    }

    // combine the 4 edge streams (lanes fq, fq+16, fq+32, fq+48)
    a0 += __shfl_xor(a0, 32, 64); a0 += __shfl_xor(a0, 16, 64);
    a1 += __shfl_xor(a1, 32, 64); a1 += __shfl_xor(a1, 16, 64);
    a2 += __shfl_xor(a2, 32, 64); a2 += __shfl_xor(a2, 16, 64);
    a3 += __shfl_xor(a3, 32, 64); a3 += __shfl_xor(a3, 16, 64);
    a4 += __shfl_xor(a4, 32, 64); a4 += __shfl_xor(a4, 16, 64);
    a5 += __shfl_xor(a5, 32, 64); a5 += __shfl_xor(a5, 16, 64);
    a6 += __shfl_xor(a6, 32, 64); a6 += __shfl_xor(a6, 16, 64);
    a7 += __shfl_xor(a7, 32, 64); a7 += __shfl_xor(a7, 16, 64);

    // distributed epilogue: group g handles feats (8fq+2g, 8fq+2g+1)
    float s0 = (g & 2) ? ((g & 1) ? a6 : a4) : ((g & 1) ? a2 : a0);
    float s1 = (g & 2) ? ((g & 1) ? a7 : a5) : ((g & 1) ? a3 : a1);
    f32x2 sf = __builtin_amdgcn_cvt_pk_f32_fp8((int)sv, false);
    s0 += sf.x;                          // self loop (row pre-scaled)
    s1 += sf.y;
    float dn = dis[node];
    float2 bv = ((const float2*)bias)[fq * 4 + g];
    float o0 = fmaf(dn, s0, bv.x);
    float o1 = fmaf(dn, s1, bv.y);
    if (DO_TANH) { o0 = fast_tanh(o0); o1 = fast_tanh(o1); }
    unsigned o = (unsigned)f2bf(o0) | ((unsigned)f2bf(o1) << 16);
    outp[(size_t)node * 64 + fq * 4 + g] = o;   // bf16 row (64 uints)
}

// ---- fused pool + head: 256 threads (4 waves) per graph, bf16 act ---------
__global__ __launch_bounds__(256) void pool_head(const unsigned* __restrict__ actb,
    const int* __restrict__ batch, const float* __restrict__ Wout,
    const float* __restrict__ bout, float* __restrict__ out, int n, int C) {
    __shared__ float psum[4][128];
    __shared__ float l[16];
    __shared__ float stats[2];
    int g = blockIdx.x;
    int t = threadIdx.x;
    int w = t >> 6;
    int lane = t & 63;
    int lo = 0, hi = n;
    while (lo < hi) { int mid = (lo + hi) >> 1; if (batch[mid] < g) lo = mid + 1; else hi = mid; }
    int lo1 = lo, hi1 = n;
    while (lo1 < hi1) { int mid = (lo1 + hi1) >> 1; if (batch[mid] < g + 1) lo1 = mid + 1; else hi1 = mid; }
    float ax = 0.f, ay = 0.f;
    for (int i = lo + w; i < lo1; i += 4) {
        unsigned v = actb[(size_t)i * 64 + lane];     // 2 bf16 feats
        ax += bf_lo(v);
        ay += bf_hi(v);
    }
    psum[w][2 * lane]     = ax;
    psum[w][2 * lane + 1] = ay;
    __syncthreads();
    if (w == 0) {
        int cnt = lo1 - lo;
        float inv = 1.0f / (float)(cnt > 0 ? cnt : 1);
        float sx = (psum[0][2 * lane] + psum[1][2 * lane])
                 + (psum[2][2 * lane] + psum[3][2 * lane]);
        float sy = (psum[0][2 * lane + 1] + psum[1][2 * lane + 1])
                 + (psum[2][2 * lane + 1] + psum[3][2 * lane + 1]);
        psum[0][2 * lane]     = sx * inv;   // reuse psum[0] as pooled
        psum[0][2 * lane + 1] = sy * inv;
    }
    __syncthreads();
    if (t < C) {
        float acc = bout[t];
        for (int f = 0; f < 128; ++f)
            acc = fmaf(psum[0][f], Wout[(size_t)f * C + t], acc);
        l[t] = acc;
    }
    __syncthreads();
    if (t == 0) {
        float m = -1e30f;
        for (int c = 0; c < C; ++c) m = fmaxf(m, l[c]);
        float s = 0.f;
        for (int c = 0; c < C; ++c) s += expf(l[c] - m);
        stats[0] = m;
        stats[1] = logf(s);
    }
    __syncthreads();
    if (t < C) out[(size_t)g * C + t] = l[t] - stats[0] - stats[1];
}

// ---------------------------------------------------------------------------
extern "C" void kernel_launch(void* const* d_in, const int* in_sizes, int n_in,
                              void* d_out, int out_size, void* d_ws, size_t ws_size,
                              hipStream_t stream) {
    const float* x     = (const float*)d_in[0];
    const int*   edge  = (const int*)d_in[1];
    const int*   batch = (const int*)d_in[2];
    const float* W0 = (const float*)d_in[3];
    const float* b0 = (const float*)d_in[4];
    const float* W1 = (const float*)d_in[5];
    const float* b1 = (const float*)d_in[6];
    const float* W2 = (const float*)d_in[7];
    const float* b2 = (const float*)d_in[8];
    const float* Wout = (const float*)d_in[9];
    const float* bout = (const float*)d_in[10];
    float* out = (float*)d_out;

    const int N = in_sizes[0] / 128;   // 50000 (< 65536 required for packing)
    const int E = in_sizes[1] / 2;     // 1600000
    const int C = in_sizes[10];        // 10
    const int G = out_size / C;        // 512

    const int* src = edge;
    const int* dst = edge + E;

    const int NBLK = (E + BLK_EDGES - 1) / BLK_EDGES;  // 391
    const int NB   = (N + 511) / 512;                  // 98 buckets
    const int NBQ  = NB * NBLK;                        // 38318 scan entries
    const int PREPB = (3 * 16384) / 256;               // 192 weight-prep blocks

    char* p = (char*)d_ws;
    auto alloc = [&](size_t bytes) -> void* {
        void* r = (void*)p;
        p += (bytes + 255) & ~(size_t)255;
        return r;
    };
    unsigned char* hs = (unsigned char*)alloc((size_t)(N + 1) * 128); // fp8 table + zero row
    unsigned* actb = (unsigned*)alloc((size_t)N * 128 * 2);       // bf16 act
    float* dis    = (float*)alloc((size_t)N * 4);
    int*   off    = (int*)alloc((size_t)(N + 1) * 4);
    int*   P      = (int*)alloc((size_t)(NBQ + 1) * 4);
    int*   bsum   = (int*)alloc(256 * 4);
    int*   boff   = (int*)alloc(256 * 4);
    unsigned* packed = (unsigned*)alloc((size_t)E * 4);
    unsigned short* csr16 = (unsigned short*)alloc((size_t)(E + 16) * 2);
    unsigned short* wt0 = (unsigned short*)alloc(128 * 128 * 2);
    unsigned short* wt1 = (unsigned short*)alloc(128 * 128 * 2);
    unsigned short* wt2 = (unsigned short*)alloc(128 * 128 * 2);

    const int sb = (NBQ + 255) / 256;   // 150 (<=256 required by scan_top)

    // CSR build + weight prep (fused into the first launch's extra blocks)
    blk_hist_prep<<<NBLK + PREPB, 256, 0, stream>>>(dst, P, E, NBLK, NB,
                                                    W0, W1, W2, wt0, wt1, wt2,
                                                    hs, N);
    scan_block<<<sb, 256, 0, stream>>>(P, P, bsum, NBQ);
    scan_top<<<1, 256, 0, stream>>>(bsum, boff, sb);
    scatter_packed<<<NBLK, 256, 0, stream>>>(src, dst, P, boff, packed, E, NBLK, NB);
    bucket_build<<<NB, 256, 0, stream>>>(packed, P, boff, off, dis, csr16, E, NBLK, N, NB);

    const int gb = (N + 63) / 64;       // 782 blocks of 256 threads (16 rows/wave)
    const int ab = (N + NPB - 1) / NPB; // 6250 blocks of 512 threads

    gemm_mfma<1><<<gb, 256, 0, stream>>>(x,    wt0, dis, hs, N);
    aggregate3<1><<<ab, 512, 0, stream>>>(hs, csr16, off, dis, b0, actb, N);
    gemm_mfma<0><<<gb, 256, 0, stream>>>(actb, wt1, dis, hs, N);
    aggregate3<1><<<ab, 512, 0, stream>>>(hs, csr16, off, dis, b1, actb, N);
    gemm_mfma<0><<<gb, 256, 0, stream>>>(actb, wt2, dis, hs, N);
    aggregate3<0><<<ab, 512, 0, stream>>>(hs, csr16, off, dis, b2, actb, N);

    pool_head<<<G, 256, 0, stream>>>(actb, batch, Wout, bout, out, N, C);
}

// Round 9
// 296.817 us; speedup vs baseline: 1.2051x; 1.2051x over previous
//
#include <hip/hip_runtime.h>
#include <math.h>

// ---------------------------------------------------------------------------
// GCN: 3x (MFMA GEMM(+dis scale, fp8 table out) -> pull-aggregate -> tanh)
//      -> fused pool+head
// R24: revert to R22 structure (R23's staging removal turned the index->row
//      dependent chain into global->global, +17us/layer — eidx LDS staging
//      restored). On top: f32x2 packed accumulators in the edge loop so the
//      8 scalar adds per uint2 become 4 v_pk_add_f32 (VOP3P) — 12 -> 8 VALU
//      inst per 8 bytes on the dominant stream. Scalar unpack only at the
//      per-node epilogue. gemm/csr/pool identical to R22.
// ---------------------------------------------------------------------------

#define BLK_EDGES 4096
#define MAXB 128          // max dst-buckets for CSR build (N<=65536)
#define ECAP 4096         // LDS edge-index capacity per aggregate block
#define NPB 8             // nodes per aggregate block (8 waves x 1 node)
#define WS_STRIDE 136     // LDS row stride for W^T (elements; 272B, 16B-aligned)

typedef __attribute__((ext_vector_type(8))) short bf16x8;
typedef __attribute__((ext_vector_type(4))) float f32x4;
typedef __attribute__((ext_vector_type(2))) float f32x2;

static __device__ inline unsigned short f2bf(float f) {
    unsigned u = __float_as_uint(f);
    unsigned r = (u + 0x7FFFu + ((u >> 16) & 1u)) >> 16;   // RNE
    return (unsigned short)r;
}
static __device__ inline float bf_lo(unsigned u) { return __uint_as_float(u << 16); }
static __device__ inline float bf_hi(unsigned u) { return __uint_as_float(u & 0xFFFF0000u); }
static __device__ inline unsigned char f2fp8(float v) {
    v = fminf(fmaxf(v, -240.f), 240.f);                    // avoid e4m3 NaN
    int u = __builtin_amdgcn_cvt_pk_fp8_f32(v, v, 0, false);
    return (unsigned char)(u & 0xFF);
}
// tanh(x) = sign(x) * (1 - 2/(1+e^{2|x|})) — v_exp + v_rcp, ~6 inst.
static __device__ inline float fast_tanh(float x) {
    float ax = fabsf(x);
    float e = __expf(2.0f * ax);
    float r = fmaf(-2.0f, __builtin_amdgcn_rcpf(e + 1.0f), 1.0f);
    return copysignf(r, x);
}

// ---- bucket histogram (blocks < NBLK) + weight transpose (blocks >= NBLK) -
// Also zeroes the hs "zero row" (row N) used by branchless masked gathers.
__global__ __launch_bounds__(256) void blk_hist_prep(const int* __restrict__ dst,
        int* __restrict__ histT, int E, int NBLK, int NB,
        const float* __restrict__ W0, const float* __restrict__ W1,
        const float* __restrict__ W2, unsigned short* __restrict__ wt0,
        unsigned short* __restrict__ wt1, unsigned short* __restrict__ wt2,
        unsigned char* __restrict__ hs, int N) {
    __shared__ int h[MAXB];
    int blk = blockIdx.x, t = threadIdx.x;
    if (blk >= NBLK) {
        if (blk == NBLK && t < 32)            // zero row N of hs (128B)
            ((unsigned*)(hs + (size_t)N * 128))[t] = 0u;
        int i = (blk - NBLK) * 256 + t;       // covers 3*16384 exactly (192 blocks)
        int w = i >> 14, j = i & 16383;
        int k = j >> 7, n2 = j & 127;
        const float* Wp = (w == 0) ? W0 : (w == 1) ? W1 : W2;
        unsigned short* Wt = (w == 0) ? wt0 : (w == 1) ? wt1 : wt2;
        Wt[n2 * 128 + k] = f2bf(Wp[k * 128 + n2]);
        return;
    }
    for (int i = t; i < NB; i += 256) h[i] = 0;
    __syncthreads();
    int lo = blk * BLK_EDGES;
    int hi = min(E, lo + BLK_EDGES);
    for (int i = lo + t; i < hi; i += 256)
        atomicAdd(&h[dst[i] >> 9], 1);
    __syncthreads();
    for (int i = t; i < NB; i += 256) histT[i * NBLK + blk] = h[i];
}

// ---- 2-kernel scan (per-chunk exclusive + chunk offsets; consumers fold) --
__global__ void scan_block(const int* __restrict__ cnt, int* __restrict__ off,
                           int* __restrict__ bsum, int n) {
    __shared__ int lds[256];
    int t = threadIdx.x;
    int i = blockIdx.x * 256 + t;
    int v = (i < n) ? cnt[i] : 0;
    lds[t] = v;
    __syncthreads();
    for (int d = 1; d < 256; d <<= 1) {
        int add = (t >= d) ? lds[t - d] : 0;
        __syncthreads();
        lds[t] += add;
        __syncthreads();
    }
    if (i < n) off[i] = lds[t] - v;      // exclusive within 256-chunk
    if (t == 255) bsum[blockIdx.x] = lds[255];
}

__global__ void scan_top(const int* __restrict__ bsum, int* __restrict__ boff,
                         int nblocks) {
    __shared__ int lds[256];
    int t = threadIdx.x;
    int v = (t < nblocks) ? bsum[t] : 0;
    lds[t] = v;
    __syncthreads();
    for (int d = 1; d < 256; d <<= 1) {
        int add = (t >= d) ? lds[t - d] : 0;
        __syncthreads();
        lds[t] += add;
        __syncthreads();
    }
    if (t < nblocks) boff[t] = lds[t] - v;   // exclusive chunk offsets
}

// ---- scatter packed edges into private (block,bucket) runs ----------------
__global__ __launch_bounds__(256) void scatter_packed(const int* __restrict__ src,
        const int* __restrict__ dst, const int* __restrict__ P,
        const int* __restrict__ boff, unsigned* __restrict__ packed,
        int E, int NBLK, int NB) {
    __shared__ int cur[MAXB];
    int blk = blockIdx.x, t = threadIdx.x;
    for (int i = t; i < NB; i += 256) {
        int idx = i * NBLK + blk;
        cur[i] = P[idx] + boff[idx >> 8];
    }
    __syncthreads();
    int lo = blk * BLK_EDGES;
    int hi = min(E, lo + BLK_EDGES);
    for (int i = lo + t; i < hi; i += 256) {
        int d = dst[i];
        int pos = atomicAdd(&cur[d >> 9], 1);   // LDS atomic, block-local
        packed[pos] = ((unsigned)d << 16) | (unsigned)src[i];
    }
}

// ---- per-bucket: node counts, local scan -> off/dis, fill ushort CSR ------
__global__ __launch_bounds__(256) void bucket_build(const unsigned* __restrict__ packed,
        const int* __restrict__ P, const int* __restrict__ boff, int* __restrict__ off,
        float* __restrict__ dis, unsigned short* __restrict__ csr16,
        int E, int NBLK, int N, int NB) {
    __shared__ int cnt[512];
    __shared__ int loc[512];
    __shared__ int ps[256];
    int b = blockIdx.x, t = threadIdx.x;
    int i0 = b * NBLK, i1 = (b + 1) * NBLK;
    int start = P[i0] + boff[i0 >> 8];
    int end   = (b == NB - 1) ? E : (P[i1] + boff[i1 >> 8]);
    cnt[t] = 0; cnt[t + 256] = 0;
    __syncthreads();
    for (int i = start + t; i < end; i += 256)
        atomicAdd(&cnt[(packed[i] >> 16) & 511], 1);
    __syncthreads();
    int c0 = cnt[2 * t], c1 = cnt[2 * t + 1];
    ps[t] = c0 + c1;
    __syncthreads();
    for (int d = 1; d < 256; d <<= 1) {
        int add = (t >= d) ? ps[t - d] : 0;
        __syncthreads();
        ps[t] += add;
        __syncthreads();
    }
    int pexcl = ps[t] - (c0 + c1);
    loc[2 * t]     = start + pexcl;
    loc[2 * t + 1] = start + pexcl + c0;
    __syncthreads();
    int node0 = b * 512;
    for (int l = t; l < 512; l += 256) {
        int node = node0 + l;
        if (node < N) {
            off[node] = loc[l];
            dis[node] = rsqrtf((float)cnt[l] + 1.0f);
        }
    }
    if (b == NB - 1 && t == 0) off[N] = E;
    __syncthreads();
    for (int i = start + t; i < end; i += 256) {
        unsigned p = packed[i];
        int l = (p >> 16) & 511;
        int pos = atomicAdd(&loc[l], 1);
        csr16[pos] = (unsigned short)(p & 0xFFFFu);
    }
}

// ---- MFMA GEMM: Hs8[r] = fp8( dis[r] * (A[r] @ W) ) -----------------------
// 256 threads (4 waves), 128 rows per block.
template<int IN_F32>
__global__ __launch_bounds__(256) void gemm_mfma(const void* __restrict__ Av,
        const unsigned short* __restrict__ Wt, const float* __restrict__ dis,
        unsigned char* __restrict__ Hs8, int n) {
    __shared__ unsigned short Ws[128 * WS_STRIDE];   // 34.8 KB
    int t = threadIdx.x;
    for (int i = t; i < 128 * 16; i += 256) {
        int r = i >> 4, j = i & 15;
        uint4 u = ((const uint4*)(Wt + r * 128))[j];
        *(uint4*)&Ws[r * WS_STRIDE + j * 8] = u;
    }
    __syncthreads();

    int wave = t >> 6, lane = t & 63;
    int quad = lane >> 4, l16 = lane & 15;
    int row0 = blockIdx.x * 128 + wave * 32;

    int ra0 = row0 + l16;      if (ra0 >= n) ra0 = n - 1;
    int ra1 = row0 + 16 + l16; if (ra1 >= n) ra1 = n - 1;

    f32x4 acc[2][8];
    const f32x4 z = {0.f, 0.f, 0.f, 0.f};
#pragma unroll
    for (int mi = 0; mi < 2; ++mi)
#pragma unroll
        for (int ni = 0; ni < 8; ++ni) acc[mi][ni] = z;

#pragma unroll
    for (int ks = 0; ks < 4; ++ks) {
        int kof = ks * 32 + quad * 8;
        bf16x8 a0, a1;
        if (IN_F32) {
            const float* A0 = (const float*)Av + (size_t)ra0 * 128 + kof;
            const float* A1 = (const float*)Av + (size_t)ra1 * 128 + kof;
            float4 p0 = ((const float4*)A0)[0], p1 = ((const float4*)A0)[1];
            float4 q0 = ((const float4*)A1)[0], q1 = ((const float4*)A1)[1];
            a0[0] = (short)f2bf(p0.x); a0[1] = (short)f2bf(p0.y);
            a0[2] = (short)f2bf(p0.z); a0[3] = (short)f2bf(p0.w);
            a0[4] = (short)f2bf(p1.x); a0[5] = (short)f2bf(p1.y);
            a0[6] = (short)f2bf(p1.z); a0[7] = (short)f2bf(p1.w);
            a1[0] = (short)f2bf(q0.x); a1[1] = (short)f2bf(q0.y);
            a1[2] = (short)f2bf(q0.z); a1[3] = (short)f2bf(q0.w);
            a1[4] = (short)f2bf(q1.x); a1[5] = (short)f2bf(q1.y);
            a1[6] = (short)f2bf(q1.z); a1[7] = (short)f2bf(q1.w);
        } else {
            a0 = *(const bf16x8*)((const unsigned short*)Av + (size_t)ra0 * 128 + kof);
            a1 = *(const bf16x8*)((const unsigned short*)Av + (size_t)ra1 * 128 + kof);
        }
        bf16x8 b[8];
#pragma unroll
        for (int ni = 0; ni < 8; ++ni)
            b[ni] = *(const bf16x8*)&Ws[(ni * 16 + l16) * WS_STRIDE + kof];
#pragma unroll
        for (int ni = 0; ni < 8; ++ni) {
            acc[0][ni] = __builtin_amdgcn_mfma_f32_16x16x32_bf16(a0, b[ni], acc[0][ni], 0, 0, 0);
            acc[1][ni] = __builtin_amdgcn_mfma_f32_16x16x32_bf16(a1, b[ni], acc[1][ni], 0, 0, 0);
        }
    }
#pragma unroll
    for (int mi = 0; mi < 2; ++mi) {
        int rb = row0 + mi * 16 + quad * 4;
#pragma unroll
        for (int reg = 0; reg < 4; ++reg) {
            int r = rb + reg;
            if (r < n) {
                float dv = dis[r];
#pragma unroll
                for (int ni = 0; ni < 8; ++ni)
                    Hs8[(size_t)r * 128 + ni * 16 + l16] = f2fp8(acc[mi][ni][reg] * dv);
            }
        }
    }
}

// ---- pull aggregation over fp8 table: blocked, staged, branchless batches -
// 8 nodes per 512-thread block (8 waves x 1 node). eidx LDS staging keeps
// the index->row dependent chain LDS->global (R23 showed global->global
// costs +17us/layer). 16-edge batches (4 j-steps x 4 edge streams), uint2
// per lane, OOR slots clamp to zeroed row N. f32x2 packed accumulators
// (v_pk_add_f32), scalar unpack at the per-node epilogue only.
template<int DO_TANH>
__global__ __launch_bounds__(512) void aggregate3(const unsigned char* __restrict__ hs,
    const unsigned short* __restrict__ csr, const int* __restrict__ off,
    const float* __restrict__ dis, const float* __restrict__ bias,
    unsigned* __restrict__ outp, int n) {
    __shared__ unsigned short eidx[ECAP + 16];   // +16: speculative reads
    int t = threadIdx.x;
    int node0 = blockIdx.x * NPB;
    int b0 = off[node0];
    int top = node0 + NPB < n ? node0 + NPB : n;
    int bN = off[top];
    int mblk = bN - b0;
    bool staged = (mblk <= ECAP);
    if (staged)
        for (int i = t; i < mblk; i += 512) eidx[i] = csr[b0 + i];
    __syncthreads();

    int node = node0 + (t >> 6);
    if (node >= n) return;
    int lane = t & 63;
    int g = lane >> 4;                      // edge stream 0..3
    int fq = lane & 15;                     // feature octet
    unsigned fob = (unsigned)fq << 3;       // feature byte offset in row

    int e0 = off[node];
    int e1 = off[node + 1];
    int le0 = e0 - b0;
    int m = e1 - e0;

    // self-loop bytes for this lane's pair (feats 8fq+2g, +1): issue early
    unsigned sv = *(const unsigned short*)(hs + (((unsigned)node) << 7) + fob + 2 * g);

    const f32x2 z2 = {0.f, 0.f};
    f32x2 c01 = z2, c23 = z2, c45 = z2, c67 = z2;   // packed accumulators
    auto cadd = [&](uint2 v) {
        c01 += __builtin_amdgcn_cvt_pk_f32_fp8((int)v.x, false);
        c23 += __builtin_amdgcn_cvt_pk_f32_fp8((int)v.x, true);
        c45 += __builtin_amdgcn_cvt_pk_f32_fp8((int)v.y, false);
        c67 += __builtin_amdgcn_cvt_pk_f32_fp8((int)v.y, true);
    };
    uint2 va[4], vb[4];
    auto sumB = [&](uint2* v) {
#pragma unroll
        for (int j = 0; j < 4; ++j) cadd(v[j]);
    };
    // branchless batch: edge e = i + g + 4j; e >= m -> zero row n
    auto loadL = [&](int i, uint2* v) {
#pragma unroll
        for (int j = 0; j < 4; ++j) {
            int e = i + g + 4 * j;
            int idx = eidx[le0 + e];                 // speculative (padded)
            idx = (e < m) ? idx : n;                 // clamp to zero row
            v[j] = *(const uint2*)(hs + ((unsigned)idx << 7) + fob);
        }
    };
    auto loadG = [&](int i, uint2* v) {
#pragma unroll
        for (int j = 0; j < 4; ++j) {
            int e = i + g + 4 * j;
            int idx = csr[e0 + e];                   // speculative (padded)
            idx = (e < m) ? idx : n;                 // clamp to zero row
            v[j] = *(const uint2*)(hs + ((unsigned)idx << 7) + fob);
        }
    };

    int B = (m + 15) >> 4;          // 16-edge batches, no tail
    if (B) {
        if (staged) {
            loadL(0, va);
            int k = 1;
            for (; k + 1 < B; k += 2) {
                loadL(k << 4, vb);       sumB(va);
                loadL((k + 1) << 4, va); sumB(vb);
            }
            if (k < B) { loadL(k << 4, vb); sumB(va); sumB(vb); }
            else       { sumB(va); }
        } else {
            loadG(0, va);
            int k = 1;
            for (; k + 1 < B; k += 2) {
                loadG(k << 4, vb);       sumB(va);
                loadG((k + 1) << 4, va); sumB(vb);
            }
            if (k < B) { loadG(k << 4, vb); sumB(va); sumB(vb); }
            else       { sumB(va); }
        }
    }

    float a0 = c01.x, a1 = c01.y, a2 = c23.x, a3 = c23.y;
    float a4 = c45.x, a5 = c45.y, a6 = c67.x, a7 = c67.y;

    // combine the 4 edge streams (lanes fq, fq+16, fq+32, fq+48)
    a0 += __shfl_xor(a0, 32, 64); a0 += __shfl_xor(a0, 16, 64);
    a1 += __shfl_xor(a1, 32, 64); a1 += __shfl_xor(a1, 16, 64);
    a2 += __shfl_xor(a2, 32, 64); a2 += __shfl_xor(a2, 16, 64);
    a3 += __shfl_xor(a3, 32, 64); a3 += __shfl_xor(a3, 16, 64);
    a4 += __shfl_xor(a4, 32, 64); a4 += __shfl_xor(a4, 16, 64);
    a5 += __shfl_xor(a5, 32, 64); a5 += __shfl_xor(a5, 16, 64);
    a6 += __shfl_xor(a6, 32, 64); a6 += __shfl_xor(a6, 16, 64);
    a7 += __shfl_xor(a7, 32, 64); a7 += __shfl_xor(a7, 16, 64);

    // distributed epilogue: group g handles feats (8fq+2g, 8fq+2g+1)
    float s0 = (g & 2) ? ((g & 1) ? a6 : a4) : ((g & 1) ? a2 : a0);
    float s1 = (g & 2) ? ((g & 1) ? a7 : a5) : ((g & 1) ? a3 : a1);
    f32x2 sf = __builtin_amdgcn_cvt_pk_f32_fp8((int)sv, false);
    s0 += sf.x;                          // self loop (row pre-scaled)
    s1 += sf.y;
    float dn = dis[node];
    float2 bv = ((const float2*)bias)[fq * 4 + g];
    float o0 = fmaf(dn, s0, bv.x);
    float o1 = fmaf(dn, s1, bv.y);
    if (DO_TANH) { o0 = fast_tanh(o0); o1 = fast_tanh(o1); }
    unsigned o = (unsigned)f2bf(o0) | ((unsigned)f2bf(o1) << 16);
    outp[(size_t)node * 64 + fq * 4 + g] = o;   // bf16 row (64 uints)
}

// ---- fused pool + head: 256 threads (4 waves) per graph, bf16 act ---------
__global__ __launch_bounds__(256) void pool_head(const unsigned* __restrict__ actb,
    const int* __restrict__ batch, const float* __restrict__ Wout,
    const float* __restrict__ bout, float* __restrict__ out, int n, int C) {
    __shared__ float psum[4][128];
    __shared__ float l[16];
    __shared__ float stats[2];
    int g = blockIdx.x;
    int t = threadIdx.x;
    int w = t >> 6;
    int lane = t & 63;
    int lo = 0, hi = n;
    while (lo < hi) { int mid = (lo + hi) >> 1; if (batch[mid] < g) lo = mid + 1; else hi = mid; }
    int lo1 = lo, hi1 = n;
    while (lo1 < hi1) { int mid = (lo1 + hi1) >> 1; if (batch[mid] < g + 1) lo1 = mid + 1; else hi1 = mid; }
    float ax = 0.f, ay = 0.f;
    for (int i = lo + w; i < lo1; i += 4) {
        unsigned v = actb[(size_t)i * 64 + lane];     // 2 bf16 feats
        ax += bf_lo(v);
        ay += bf_hi(v);
    }
    psum[w][2 * lane]     = ax;
    psum[w][2 * lane + 1] = ay;
    __syncthreads();
    if (w == 0) {
        int cnt = lo1 - lo;
        float inv = 1.0f / (float)(cnt > 0 ? cnt : 1);
        float sx = (psum[0][2 * lane] + psum[1][2 * lane])
                 + (psum[2][2 * lane] + psum[3][2 * lane]);
        float sy = (psum[0][2 * lane + 1] + psum[1][2 * lane + 1])
                 + (psum[2][2 * lane + 1] + psum[3][2 * lane + 1]);
        psum[0][2 * lane]     = sx * inv;   // reuse psum[0] as pooled
        psum[0][2 * lane + 1] = sy * inv;
    }
    __syncthreads();
    if (t < C) {
        float acc = bout[t];
        for (int f = 0; f < 128; ++f)
            acc = fmaf(psum[0][f], Wout[(size_t)f * C + t], acc);
        l[t] = acc;
    }
    __syncthreads();
    if (t == 0) {
        float m = -1e30f;
        for (int c = 0; c < C; ++c) m = fmaxf(m, l[c]);
        float s = 0.f;
        for (int c = 0; c < C; ++c) s += expf(l[c] - m);
        stats[0] = m;
        stats[1] = logf(s);
    }
    __syncthreads();
    if (t < C) out[(size_t)g * C + t] = l[t] - stats[0] - stats[1];
}

// ---------------------------------------------------------------------------
extern "C" void kernel_launch(void* const* d_in, const int* in_sizes, int n_in,
                              void* d_out, int out_size, void* d_ws, size_t ws_size,
                              hipStream_t stream) {
    const float* x     = (const float*)d_in[0];
    const int*   edge  = (const int*)d_in[1];
    const int*   batch = (const int*)d_in[2];
    const float* W0 = (const float*)d_in[3];
    const float* b0 = (const float*)d_in[4];
    const float* W1 = (const float*)d_in[5];
    const float* b1 = (const float*)d_in[6];
    const float* W2 = (const float*)d_in[7];
    const float* b2 = (const float*)d_in[8];
    const float* Wout = (const float*)d_in[9];
    const float* bout = (const float*)d_in[10];
    float* out = (float*)d_out;

    const int N = in_sizes[0] / 128;   // 50000 (< 65536 required for packing)
    const int E = in_sizes[1] / 2;     // 1600000
    const int C = in_sizes[10];        // 10
    const int G = out_size / C;        // 512

    const int* src = edge;
    const int* dst = edge + E;

    const int NBLK = (E + BLK_EDGES - 1) / BLK_EDGES;  // 391
    const int NB   = (N + 511) / 512;                  // 98 buckets
    const int NBQ  = NB * NBLK;                        // 38318 scan entries
    const int PREPB = (3 * 16384) / 256;               // 192 weight-prep blocks

    char* p = (char*)d_ws;
    auto alloc = [&](size_t bytes) -> void* {
        void* r = (void*)p;
        p += (bytes + 255) & ~(size_t)255;
        return r;
    };
    unsigned char* hs = (unsigned char*)alloc((size_t)(N + 1) * 128); // fp8 table + zero row
    unsigned* actb = (unsigned*)alloc((size_t)N * 128 * 2);       // bf16 act
    float* dis    = (float*)alloc((size_t)N * 4);
    int*   off    = (int*)alloc((size_t)(N + 1) * 4);
    int*   P      = (int*)alloc((size_t)(NBQ + 1) * 4);
    int*   bsum   = (int*)alloc(256 * 4);
    int*   boff   = (int*)alloc(256 * 4);
    unsigned* packed = (unsigned*)alloc((size_t)E * 4);
    unsigned short* csr16 = (unsigned short*)alloc((size_t)(E + 16) * 2);
    unsigned short* wt0 = (unsigned short*)alloc(128 * 128 * 2);
    unsigned short* wt1 = (unsigned short*)alloc(128 * 128 * 2);
    unsigned short* wt2 = (unsigned short*)alloc(128 * 128 * 2);

    const int sb = (NBQ + 255) / 256;   // 150 (<=256 required by scan_top)

    // CSR build + weight prep (fused into the first launch's extra blocks)
    blk_hist_prep<<<NBLK + PREPB, 256, 0, stream>>>(dst, P, E, NBLK, NB,
                                                    W0, W1, W2, wt0, wt1, wt2,
                                                    hs, N);
    scan_block<<<sb, 256, 0, stream>>>(P, P, bsum, NBQ);
    scan_top<<<1, 256, 0, stream>>>(bsum, boff, sb);
    scatter_packed<<<NBLK, 256, 0, stream>>>(src, dst, P, boff, packed, E, NBLK, NB);
    bucket_build<<<NB, 256, 0, stream>>>(packed, P, boff, off, dis, csr16, E, NBLK, N, NB);

    const int gb = (N + 127) / 128;     // 391 blocks of 256 threads
    const int ab = (N + NPB - 1) / NPB; // 6250 blocks of 512 threads

    gemm_mfma<1><<<gb, 256, 0, stream>>>(x,    wt0, dis, hs, N);
    aggregate3<1><<<ab, 512, 0, stream>>>(hs, csr16, off, dis, b0, actb, N);
    gemm_mfma<0><<<gb, 256, 0, stream>>>(actb, wt1, dis, hs, N);
    aggregate3<1><<<ab, 512, 0, stream>>>(hs, csr16, off, dis, b1, actb, N);
    gemm_mfma<0><<<gb, 256, 0, stream>>>(actb, wt2, dis, hs, N);
    aggregate3<0><<<ab, 512, 0, stream>>>(hs, csr16, off, dis, b2, actb, N);

    pool_head<<<G, 256, 0, stream>>>(actb, batch, Wout, bout, out, N, C);
}

// Round 10
// 293.775 us; speedup vs baseline: 1.2176x; 1.0104x over previous
//
#include <hip/hip_runtime.h>
#include <math.h>

// ---------------------------------------------------------------------------
// GCN: 3x (MFMA GEMM(+dis scale, fp8 table out) -> pull-aggregate -> tanh)
//      -> fused pool+head
// R25: gemm epilogue packed stores. W^T rows staged into LDS slot
//      ((r&7)<<4)|(r>>3) so MFMA ni computes output col l16*8+ni; each
//      lane's 8 outputs are contiguous bytes -> pack via 4 cvt_pk_fp8 and
//      store ONE uint2 instead of 64 single-byte stores per lane (VMEM
//      issue-slot waste was ~56 slots/wave). LDS read pattern and hs layout
//      byte-identical (position == feature). aggregate/csr/pool = R24.
// ---------------------------------------------------------------------------

#define BLK_EDGES 4096
#define MAXB 128          // max dst-buckets for CSR build (N<=65536)
#define ECAP 4096         // LDS edge-index capacity per aggregate block
#define NPB 8             // nodes per aggregate block (8 waves x 1 node)
#define WS_STRIDE 136     // LDS row stride for W^T (elements; 272B, 16B-aligned)

typedef __attribute__((ext_vector_type(8))) short bf16x8;
typedef __attribute__((ext_vector_type(4))) float f32x4;
typedef __attribute__((ext_vector_type(2))) float f32x2;

static __device__ inline unsigned short f2bf(float f) {
    unsigned u = __float_as_uint(f);
    unsigned r = (u + 0x7FFFu + ((u >> 16) & 1u)) >> 16;   // RNE
    return (unsigned short)r;
}
static __device__ inline float bf_lo(unsigned u) { return __uint_as_float(u << 16); }
static __device__ inline float bf_hi(unsigned u) { return __uint_as_float(u & 0xFFFF0000u); }
static __device__ inline unsigned char f2fp8(float v) {
    v = fminf(fmaxf(v, -240.f), 240.f);                    // avoid e4m3 NaN
    int u = __builtin_amdgcn_cvt_pk_fp8_f32(v, v, 0, false);
    return (unsigned char)(u & 0xFF);
}
// tanh(x) = sign(x) * (1 - 2/(1+e^{2|x|})) — v_exp + v_rcp, ~6 inst.
static __device__ inline float fast_tanh(float x) {
    float ax = fabsf(x);
    float e = __expf(2.0f * ax);
    float r = fmaf(-2.0f, __builtin_amdgcn_rcpf(e + 1.0f), 1.0f);
    return copysignf(r, x);
}

// ---- bucket histogram (blocks < NBLK) + weight transpose (blocks >= NBLK) -
// Also zeroes the hs "zero row" (row N) used by branchless masked gathers.
__global__ __launch_bounds__(256) void blk_hist_prep(const int* __restrict__ dst,
        int* __restrict__ histT, int E, int NBLK, int NB,
        const float* __restrict__ W0, const float* __restrict__ W1,
        const float* __restrict__ W2, unsigned short* __restrict__ wt0,
        unsigned short* __restrict__ wt1, unsigned short* __restrict__ wt2,
        unsigned char* __restrict__ hs, int N) {
    __shared__ int h[MAXB];
    int blk = blockIdx.x, t = threadIdx.x;
    if (blk >= NBLK) {
        if (blk == NBLK && t < 32)            // zero row N of hs (128B)
            ((unsigned*)(hs + (size_t)N * 128))[t] = 0u;
        int i = (blk - NBLK) * 256 + t;       // covers 3*16384 exactly (192 blocks)
        int w = i >> 14, j = i & 16383;
        int k = j >> 7, n2 = j & 127;
        const float* Wp = (w == 0) ? W0 : (w == 1) ? W1 : W2;
        unsigned short* Wt = (w == 0) ? wt0 : (w == 1) ? wt1 : wt2;
        Wt[n2 * 128 + k] = f2bf(Wp[k * 128 + n2]);
        return;
    }
    for (int i = t; i < NB; i += 256) h[i] = 0;
    __syncthreads();
    int lo = blk * BLK_EDGES;
    int hi = min(E, lo + BLK_EDGES);
    for (int i = lo + t; i < hi; i += 256)
        atomicAdd(&h[dst[i] >> 9], 1);
    __syncthreads();
    for (int i = t; i < NB; i += 256) histT[i * NBLK + blk] = h[i];
}

// ---- 2-kernel scan (per-chunk exclusive + chunk offsets; consumers fold) --
__global__ void scan_block(const int* __restrict__ cnt, int* __restrict__ off,
                           int* __restrict__ bsum, int n) {
    __shared__ int lds[256];
    int t = threadIdx.x;
    int i = blockIdx.x * 256 + t;
    int v = (i < n) ? cnt[i] : 0;
    lds[t] = v;
    __syncthreads();
    for (int d = 1; d < 256; d <<= 1) {
        int add = (t >= d) ? lds[t - d] : 0;
        __syncthreads();
        lds[t] += add;
        __syncthreads();
    }
    if (i < n) off[i] = lds[t] - v;      // exclusive within 256-chunk
    if (t == 255) bsum[blockIdx.x] = lds[255];
}

__global__ void scan_top(const int* __restrict__ bsum, int* __restrict__ boff,
                         int nblocks) {
    __shared__ int lds[256];
    int t = threadIdx.x;
    int v = (t < nblocks) ? bsum[t] : 0;
    lds[t] = v;
    __syncthreads();
    for (int d = 1; d < 256; d <<= 1) {
        int add = (t >= d) ? lds[t - d] : 0;
        __syncthreads();
        lds[t] += add;
        __syncthreads();
    }
    if (t < nblocks) boff[t] = lds[t] - v;   // exclusive chunk offsets
}

// ---- scatter packed edges into private (block,bucket) runs ----------------
__global__ __launch_bounds__(256) void scatter_packed(const int* __restrict__ src,
        const int* __restrict__ dst, const int* __restrict__ P,
        const int* __restrict__ boff, unsigned* __restrict__ packed,
        int E, int NBLK, int NB) {
    __shared__ int cur[MAXB];
    int blk = blockIdx.x, t = threadIdx.x;
    for (int i = t; i < NB; i += 256) {
        int idx = i * NBLK + blk;
        cur[i] = P[idx] + boff[idx >> 8];
    }
    __syncthreads();
    int lo = blk * BLK_EDGES;
    int hi = min(E, lo + BLK_EDGES);
    for (int i = lo + t; i < hi; i += 256) {
        int d = dst[i];
        int pos = atomicAdd(&cur[d >> 9], 1);   // LDS atomic, block-local
        packed[pos] = ((unsigned)d << 16) | (unsigned)src[i];
    }
}

// ---- per-bucket: node counts, local scan -> off/dis, fill ushort CSR ------
__global__ __launch_bounds__(256) void bucket_build(const unsigned* __restrict__ packed,
        const int* __restrict__ P, const int* __restrict__ boff, int* __restrict__ off,
        float* __restrict__ dis, unsigned short* __restrict__ csr16,
        int E, int NBLK, int N, int NB) {
    __shared__ int cnt[512];
    __shared__ int loc[512];
    __shared__ int ps[256];
    int b = blockIdx.x, t = threadIdx.x;
    int i0 = b * NBLK, i1 = (b + 1) * NBLK;
    int start = P[i0] + boff[i0 >> 8];
    int end   = (b == NB - 1) ? E : (P[i1] + boff[i1 >> 8]);
    cnt[t] = 0; cnt[t + 256] = 0;
    __syncthreads();
    for (int i = start + t; i < end; i += 256)
        atomicAdd(&cnt[(packed[i] >> 16) & 511], 1);
    __syncthreads();
    int c0 = cnt[2 * t], c1 = cnt[2 * t + 1];
    ps[t] = c0 + c1;
    __syncthreads();
    for (int d = 1; d < 256; d <<= 1) {
        int add = (t >= d) ? ps[t - d] : 0;
        __syncthreads();
        ps[t] += add;
        __syncthreads();
    }
    int pexcl = ps[t] - (c0 + c1);
    loc[2 * t]     = start + pexcl;
    loc[2 * t + 1] = start + pexcl + c0;
    __syncthreads();
    int node0 = b * 512;
    for (int l = t; l < 512; l += 256) {
        int node = node0 + l;
        if (node < N) {
            off[node] = loc[l];
            dis[node] = rsqrtf((float)cnt[l] + 1.0f);
        }
    }
    if (b == NB - 1 && t == 0) off[N] = E;
    __syncthreads();
    for (int i = start + t; i < end; i += 256) {
        unsigned p = packed[i];
        int l = (p >> 16) & 511;
        int pos = atomicAdd(&loc[l], 1);
        csr16[pos] = (unsigned short)(p & 0xFFFFu);
    }
}

// ---- MFMA GEMM: Hs8[r] = fp8( dis[r] * (A[r] @ W) ) -----------------------
// 256 threads (4 waves), 128 rows per block. W^T row r staged into LDS slot
// ((r&7)<<4)|(r>>3): the unchanged b[ni]=LDSrow(ni*16+l16) read then holds
// W^T row l16*8+ni, so lane l16 computes cols 8*l16..8*l16+7 -> packed
// uint2 store per (mi,reg) row instead of 8 byte-stores.
template<int IN_F32>
__global__ __launch_bounds__(256) void gemm_mfma(const void* __restrict__ Av,
        const unsigned short* __restrict__ Wt, const float* __restrict__ dis,
        unsigned char* __restrict__ Hs8, int n) {
    __shared__ unsigned short Ws[128 * WS_STRIDE];   // 34.8 KB
    int t = threadIdx.x;
    for (int i = t; i < 128 * 16; i += 256) {
        int r = i >> 4, j = i & 15;
        uint4 u = ((const uint4*)(Wt + r * 128))[j];
        int pr = ((r & 7) << 4) | (r >> 3);          // permuted LDS slot
        *(uint4*)&Ws[pr * WS_STRIDE + j * 8] = u;
    }
    __syncthreads();

    int wave = t >> 6, lane = t & 63;
    int quad = lane >> 4, l16 = lane & 15;
    int row0 = blockIdx.x * 128 + wave * 32;

    int ra0 = row0 + l16;      if (ra0 >= n) ra0 = n - 1;
    int ra1 = row0 + 16 + l16; if (ra1 >= n) ra1 = n - 1;

    f32x4 acc[2][8];
    const f32x4 z = {0.f, 0.f, 0.f, 0.f};
#pragma unroll
    for (int mi = 0; mi < 2; ++mi)
#pragma unroll
        for (int ni = 0; ni < 8; ++ni) acc[mi][ni] = z;

#pragma unroll
    for (int ks = 0; ks < 4; ++ks) {
        int kof = ks * 32 + quad * 8;
        bf16x8 a0, a1;
        if (IN_F32) {
            const float* A0 = (const float*)Av + (size_t)ra0 * 128 + kof;
            const float* A1 = (const float*)Av + (size_t)ra1 * 128 + kof;
            float4 p0 = ((const float4*)A0)[0], p1 = ((const float4*)A0)[1];
            float4 q0 = ((const float4*)A1)[0], q1 = ((const float4*)A1)[1];
            a0[0] = (short)f2bf(p0.x); a0[1] = (short)f2bf(p0.y);
            a0[2] = (short)f2bf(p0.z); a0[3] = (short)f2bf(p0.w);
            a0[4] = (short)f2bf(p1.x); a0[5] = (short)f2bf(p1.y);
            a0[6] = (short)f2bf(p1.z); a0[7] = (short)f2bf(p1.w);
            a1[0] = (short)f2bf(q0.x); a1[1] = (short)f2bf(q0.y);
            a1[2] = (short)f2bf(q0.z); a1[3] = (short)f2bf(q0.w);
            a1[4] = (short)f2bf(q1.x); a1[5] = (short)f2bf(q1.y);
            a1[6] = (short)f2bf(q1.z); a1[7] = (short)f2bf(q1.w);
        } else {
            a0 = *(const bf16x8*)((const unsigned short*)Av + (size_t)ra0 * 128 + kof);
            a1 = *(const bf16x8*)((const unsigned short*)Av + (size_t)ra1 * 128 + kof);
        }
        bf16x8 b[8];
#pragma unroll
        for (int ni = 0; ni < 8; ++ni)
            b[ni] = *(const bf16x8*)&Ws[(ni * 16 + l16) * WS_STRIDE + kof];
#pragma unroll
        for (int ni = 0; ni < 8; ++ni) {
            acc[0][ni] = __builtin_amdgcn_mfma_f32_16x16x32_bf16(a0, b[ni], acc[0][ni], 0, 0, 0);
            acc[1][ni] = __builtin_amdgcn_mfma_f32_16x16x32_bf16(a1, b[ni], acc[1][ni], 0, 0, 0);
        }
    }
#pragma unroll
    for (int mi = 0; mi < 2; ++mi) {
        int rb = row0 + mi * 16 + quad * 4;
#pragma unroll
        for (int reg = 0; reg < 4; ++reg) {
            int r = rb + reg;
            if (r < n) {
                float dv = dis[r];
                float v[8];
#pragma unroll
                for (int ni = 0; ni < 8; ++ni)
                    v[ni] = fminf(fmaxf(acc[mi][ni][reg] * dv, -240.f), 240.f);
                int d0 = __builtin_amdgcn_cvt_pk_fp8_f32(v[0], v[1], 0, false);
                d0 = __builtin_amdgcn_cvt_pk_fp8_f32(v[2], v[3], d0, true);
                int d1 = __builtin_amdgcn_cvt_pk_fp8_f32(v[4], v[5], 0, false);
                d1 = __builtin_amdgcn_cvt_pk_fp8_f32(v[6], v[7], d1, true);
                uint2 o; o.x = (unsigned)d0; o.y = (unsigned)d1;
                *(uint2*)(Hs8 + (size_t)r * 128 + l16 * 8) = o;  // cols 8l16..+7
            }
        }
    }
}

// ---- pull aggregation over fp8 table: blocked, staged, branchless batches -
// 8 nodes per 512-thread block (8 waves x 1 node). eidx LDS staging keeps
// the index->row dependent chain LDS->global (R23: global->global costs
// +17us/layer). 16-edge batches (4 j-steps x 4 edge streams), uint2 per
// lane, OOR slots clamp to zeroed row N. f32x2 packed accumulators
// (v_pk_add_f32), scalar unpack at the per-node epilogue only.
template<int DO_TANH>
__global__ __launch_bounds__(512) void aggregate3(const unsigned char* __restrict__ hs,
    const unsigned short* __restrict__ csr, const int* __restrict__ off,
    const float* __restrict__ dis, const float* __restrict__ bias,
    unsigned* __restrict__ outp, int n) {
    __shared__ unsigned short eidx[ECAP + 16];   // +16: speculative reads
    int t = threadIdx.x;
    int node0 = blockIdx.x * NPB;
    int b0 = off[node0];
    int top = node0 + NPB < n ? node0 + NPB : n;
    int bN = off[top];
    int mblk = bN - b0;
    bool staged = (mblk <= ECAP);
    if (staged)
        for (int i = t; i < mblk; i += 512) eidx[i] = csr[b0 + i];
    __syncthreads();

    int node = node0 + (t >> 6);
    if (node >= n) return;
    int lane = t & 63;
    int g = lane >> 4;                      // edge stream 0..3
    int fq = lane & 15;                     // feature octet
    unsigned fob = (unsigned)fq << 3;       // feature byte offset in row

    int e0 = off[node];
    int e1 = off[node + 1];
    int le0 = e0 - b0;
    int m = e1 - e0;

    // self-loop bytes for this lane's pair (feats 8fq+2g, +1): issue early
    unsigned sv = *(const unsigned short*)(hs + (((unsigned)node) << 7) + fob + 2 * g);

    const f32x2 z2 = {0.f, 0.f};
    f32x2 c01 = z2, c23 = z2, c45 = z2, c67 = z2;   // packed accumulators
    auto cadd = [&](uint2 v) {
        c01 += __builtin_amdgcn_cvt_pk_f32_fp8((int)v.x, false);
        c23 += __builtin_amdgcn_cvt_pk_f32_fp8((int)v.x, true);
        c45 += __builtin_amdgcn_cvt_pk_f32_fp8((int)v.y, false);
        c67 += __builtin_amdgcn_cvt_pk_f32_fp8((int)v.y, true);
    };
    uint2 va[4], vb[4];
    auto sumB = [&](uint2* v) {
#pragma unroll
        for (int j = 0; j < 4; ++j) cadd(v[j]);
    };
    // branchless batch: edge e = i + g + 4j; e >= m -> zero row n
    auto loadL = [&](int i, uint2* v) {
#pragma unroll
        for (int j = 0; j < 4; ++j) {
            int e = i + g + 4 * j;
            int idx = eidx[le0 + e];                 // speculative (padded)
            idx = (e < m) ? idx : n;                 // clamp to zero row
            v[j] = *(const uint2*)(hs + ((unsigned)idx << 7) + fob);
        }
    };
    auto loadG = [&](int i, uint2* v) {
#pragma unroll
        for (int j = 0; j < 4; ++j) {
            int e = i + g + 4 * j;
            int idx = csr[e0 + e];                   // speculative (padded)
            idx = (e < m) ? idx : n;                 // clamp to zero row
            v[j] = *(const uint2*)(hs + ((unsigned)idx << 7) + fob);
        }
    };

    int B = (m + 15) >> 4;          // 16-edge batches, no tail
    if (B) {
        if (staged) {
            loadL(0, va);
            int k = 1;
            for (; k + 1 < B; k += 2) {
                loadL(k << 4, vb);       sumB(va);
                loadL((k + 1) << 4, va); sumB(vb);
            }
            if (k < B) { loadL(k << 4, vb); sumB(va); sumB(vb); }
            else       { sumB(va); }
        } else {
            loadG(0, va);
            int k = 1;
            for (; k + 1 < B; k += 2) {
                loadG(k << 4, vb);       sumB(va);
                loadG((k + 1) << 4, va); sumB(vb);
            }
            if (k < B) { loadG(k << 4, vb); sumB(va); sumB(vb); }
            else       { sumB(va); }
        }
    }

    float a0 = c01.x, a1 = c01.y, a2 = c23.x, a3 = c23.y;
    float a4 = c45.x, a5 = c45.y, a6 = c67.x, a7 = c67.y;

    // combine the 4 edge streams (lanes fq, fq+16, fq+32, fq+48)
    a0 += __shfl_xor(a0, 32, 64); a0 += __shfl_xor(a0, 16, 64);
    a1 += __shfl_xor(a1, 32, 64); a1 += __shfl_xor(a1, 16, 64);
    a2 += __shfl_xor(a2, 32, 64); a2 += __shfl_xor(a2, 16, 64);
    a3 += __shfl_xor(a3, 32, 64); a3 += __shfl_xor(a3, 16, 64);
    a4 += __shfl_xor(a4, 32, 64); a4 += __shfl_xor(a4, 16, 64);
    a5 += __shfl_xor(a5, 32, 64); a5 += __shfl_xor(a5, 16, 64);
    a6 += __shfl_xor(a6, 32, 64); a6 += __shfl_xor(a6, 16, 64);
    a7 += __shfl_xor(a7, 32, 64); a7 += __shfl_xor(a7, 16, 64);

    // distributed epilogue: group g handles feats (8fq+2g, 8fq+2g+1)
    float s0 = (g & 2) ? ((g & 1) ? a6 : a4) : ((g & 1) ? a2 : a0);
    float s1 = (g & 2) ? ((g & 1) ? a7 : a5) : ((g & 1) ? a3 : a1);
    f32x2 sf = __builtin_amdgcn_cvt_pk_f32_fp8((int)sv, false);
    s0 += sf.x;                          // self loop (row pre-scaled)
    s1 += sf.y;
    float dn = dis[node];
    float2 bv = ((const float2*)bias)[fq * 4 + g];
    float o0 = fmaf(dn, s0, bv.x);
    float o1 = fmaf(dn, s1, bv.y);
    if (DO_TANH) { o0 = fast_tanh(o0); o1 = fast_tanh(o1); }
    unsigned o = (unsigned)f2bf(o0) | ((unsigned)f2bf(o1) << 16);
    outp[(size_t)node * 64 + fq * 4 + g] = o;   // bf16 row (64 uints)
}

// ---- fused pool + head: 256 threads (4 waves) per graph, bf16 act ---------
__global__ __launch_bounds__(256) void pool_head(const unsigned* __restrict__ actb,
    const int* __restrict__ batch, const float* __restrict__ Wout,
    const float* __restrict__ bout, float* __restrict__ out, int n, int C) {
    __shared__ float psum[4][128];
    __shared__ float l[16];
    __shared__ float stats[2];
    int g = blockIdx.x;
    int t = threadIdx.x;
    int w = t >> 6;
    int lane = t & 63;
    int lo = 0, hi = n;
    while (lo < hi) { int mid = (lo + hi) >> 1; if (batch[mid] < g) lo = mid + 1; else hi = mid; }
    int lo1 = lo, hi1 = n;
    while (lo1 < hi1) { int mid = (lo1 + hi1) >> 1; if (batch[mid] < g + 1) lo1 = mid + 1; else hi1 = mid; }
    float ax = 0.f, ay = 0.f;
    for (int i = lo + w; i < lo1; i += 4) {
        unsigned v = actb[(size_t)i * 64 + lane];     // 2 bf16 feats
        ax += bf_lo(v);
        ay += bf_hi(v);
    }
    psum[w][2 * lane]     = ax;
    psum[w][2 * lane + 1] = ay;
    __syncthreads();
    if (w == 0) {
        int cnt = lo1 - lo;
        float inv = 1.0f / (float)(cnt > 0 ? cnt : 1);
        float sx = (psum[0][2 * lane] + psum[1][2 * lane])
                 + (psum[2][2 * lane] + psum[3][2 * lane]);
        float sy = (psum[0][2 * lane + 1] + psum[1][2 * lane + 1])
                 + (psum[2][2 * lane + 1] + psum[3][2 * lane + 1]);
        psum[0][2 * lane]     = sx * inv;   // reuse psum[0] as pooled
        psum[0][2 * lane + 1] = sy * inv;
    }
    __syncthreads();
    if (t < C) {
        float acc = bout[t];
        for (int f = 0; f < 128; ++f)
            acc = fmaf(psum[0][f], Wout[(size_t)f * C + t], acc);
        l[t] = acc;
    }
    __syncthreads();
    if (t == 0) {
        float m = -1e30f;
        for (int c = 0; c < C; ++c) m = fmaxf(m, l[c]);
        float s = 0.f;
        for (int c = 0; c < C; ++c) s += expf(l[c] - m);
        stats[0] = m;
        stats[1] = logf(s);
    }
    __syncthreads();
    if (t < C) out[(size_t)g * C + t] = l[t] - stats[0] - stats[1];
}

// ---------------------------------------------------------------------------
extern "C" void kernel_launch(void* const* d_in, const int* in_sizes, int n_in,
                              void* d_out, int out_size, void* d_ws, size_t ws_size,
                              hipStream_t stream) {
    const float* x     = (const float*)d_in[0];
    const int*   edge  = (const int*)d_in[1];
    const int*   batch = (const int*)d_in[2];
    const float* W0 = (const float*)d_in[3];
    const float* b0 = (const float*)d_in[4];
    const float* W1 = (const float*)d_in[5];
    const float* b1 = (const float*)d_in[6];
    const float* W2 = (const float*)d_in[7];
    const float* b2 = (const float*)d_in[8];
    const float* Wout = (const float*)d_in[9];
    const float* bout = (const float*)d_in[10];
    float* out = (float*)d_out;

    const int N = in_sizes[0] / 128;   // 50000 (< 65536 required for packing)
    const int E = in_sizes[1] / 2;     // 1600000
    const int C = in_sizes[10];        // 10
    const int G = out_size / C;        // 512

    const int* src = edge;
    const int* dst = edge + E;

    const int NBLK = (E + BLK_EDGES - 1) / BLK_EDGES;  // 391
    const int NB   = (N + 511) / 512;                  // 98 buckets
    const int NBQ  = NB * NBLK;                        // 38318 scan entries
    const int PREPB = (3 * 16384) / 256;               // 192 weight-prep blocks

    char* p = (char*)d_ws;
    auto alloc = [&](size_t bytes) -> void* {
        void* r = (void*)p;
        p += (bytes + 255) & ~(size_t)255;
        return r;
    };
    unsigned char* hs = (unsigned char*)alloc((size_t)(N + 1) * 128); // fp8 table + zero row
    unsigned* actb = (unsigned*)alloc((size_t)N * 128 * 2);       // bf16 act
    float* dis    = (float*)alloc((size_t)N * 4);
    int*   off    = (int*)alloc((size_t)(N + 1) * 4);
    int*   P      = (int*)alloc((size_t)(NBQ + 1) * 4);
    int*   bsum   = (int*)alloc(256 * 4);
    int*   boff   = (int*)alloc(256 * 4);
    unsigned* packed = (unsigned*)alloc((size_t)E * 4);
    unsigned short* csr16 = (unsigned short*)alloc((size_t)(E + 16) * 2);
    unsigned short* wt0 = (unsigned short*)alloc(128 * 128 * 2);
    unsigned short* wt1 = (unsigned short*)alloc(128 * 128 * 2);
    unsigned short* wt2 = (unsigned short*)alloc(128 * 128 * 2);

    const int sb = (NBQ + 255) / 256;   // 150 (<=256 required by scan_top)

    // CSR build + weight prep (fused into the first launch's extra blocks)
    blk_hist_prep<<<NBLK + PREPB, 256, 0, stream>>>(dst, P, E, NBLK, NB,
                                                    W0, W1, W2, wt0, wt1, wt2,
                                                    hs, N);
    scan_block<<<sb, 256, 0, stream>>>(P, P, bsum, NBQ);
    scan_top<<<1, 256, 0, stream>>>(bsum, boff, sb);
    scatter_packed<<<NBLK, 256, 0, stream>>>(src, dst, P, boff, packed, E, NBLK, NB);
    bucket_build<<<NB, 256, 0, stream>>>(packed, P, boff, off, dis, csr16, E, NBLK, N, NB);

    const int gb = (N + 127) / 128;     // 391 blocks of 256 threads
    const int ab = (N + NPB - 1) / NPB; // 6250 blocks of 512 threads

    gemm_mfma<1><<<gb, 256, 0, stream>>>(x,    wt0, dis, hs, N);
    aggregate3<1><<<ab, 512, 0, stream>>>(hs, csr16, off, dis, b0, actb, N);
    gemm_mfma<0><<<gb, 256, 0, stream>>>(actb, wt1, dis, hs, N);
    aggregate3<1><<<ab, 512, 0, stream>>>(hs, csr16, off, dis, b1, actb, N);
    gemm_mfma<0><<<gb, 256, 0, stream>>>(actb, wt2, dis, hs, N);
    aggregate3<0><<<ab, 512, 0, stream>>>(hs, csr16, off, dis, b2, actb, N);

    pool_head<<<G, 256, 0, stream>>>(actb, batch, Wout, bout, out, N, C);
}